// Round 2
// baseline (679.090 us; speedup 1.0000x reference)
//
#include <hip/hip_runtime.h>
#include <hip/hip_bf16.h>

typedef __attribute__((ext_vector_type(8))) short s16x8;
typedef __attribute__((ext_vector_type(4))) float f32x4;
typedef unsigned short u16;
typedef unsigned int u32;

__device__ __forceinline__ u16 f2b(float f) {
    u32 u = __float_as_uint(f);
    u32 r = (u + 0x7fffu + ((u >> 16) & 1u)) >> 16;  // RNE bf16
    return (u16)r;
}
__device__ __forceinline__ u16 bfbits(float f) {
    __hip_bfloat16 h = __float2bfloat16(f);
    return *reinterpret_cast<u16*>(&h);
}

#define MFMA16(a, b, c) __builtin_amdgcn_mfma_f32_16x16x32_bf16(a, b, c, 0, 0, 0)
#define GLDS(gp, lp)                                                              \
    __builtin_amdgcn_global_load_lds((const __attribute__((address_space(1))) void*)(gp), \
                                     (__attribute__((address_space(3))) void*)(lp), 16, 0, 0)

// ---------------- elementwise: f32 -> bf16 ----------------
__global__ void k_f2b(const float* __restrict__ in, u16* __restrict__ out, int n4) {
    int i = blockIdx.x * 256 + threadIdx.x;
    if (i >= n4) return;
    float4 v = ((const float4*)in)[i];
    ushort4 o;
    o.x = f2b(v.x); o.y = f2b(v.y); o.z = f2b(v.z); o.w = f2b(v.w);
    ((ushort4*)out)[i] = o;
}

// ---------------- weight transpose+convert: W[K,N] f32 -> Wt[N,K] bf16 ----------------
__global__ void k_wtrans(const float* __restrict__ W, u16* __restrict__ Wt, int K, int N) {
    __shared__ float t[32][33];
    int bx = blockIdx.x * 32, by = blockIdx.y * 32;
    int tx = threadIdx.x, ty = threadIdx.y;
    for (int i = 0; i < 32; i += 8)
        t[ty + i][tx] = W[(size_t)(by + ty + i) * N + bx + tx];
    __syncthreads();
    for (int i = 0; i < 32; i += 8)
        Wt[(size_t)(bx + ty + i) * K + by + tx] = f2b(t[tx][ty + i]);
}

// ---------------- GEMM 128x128: C = A @ Bt^T.  EPI 0: f32 store. EPI 1: bf16(relu(acc+bias)) ----------------
template <int EPI>
__global__ __launch_bounds__(256) void gemm_bt(const u16* __restrict__ A, const u16* __restrict__ Bt,
                                               void* __restrict__ Cv, int M, int N, int K,
                                               const float* __restrict__ bias) {
    __shared__ __align__(16) short lA[128 * 64];
    __shared__ __align__(16) short lB[128 * 64];
    const int tid = threadIdx.x, lane = tid & 63, w = tid >> 6;
    const int l15 = lane & 15, lg = lane >> 4;
    const int bm = blockIdx.y, bn = blockIdx.x;
    const int wr = w >> 1, wc = w & 1;
    const int m0 = bm * 128, n0 = bn * 128;
    f32x4 acc[4][4] = {};

    for (int k0 = 0; k0 < K; k0 += 64) {
        #pragma unroll
        for (int i = 0; i < 4; i++) {
            int chunk = w * 4 + i;
            int arow = m0 + chunk * 8 + (lane >> 3);
            GLDS(A + (size_t)arow * K + k0 + (lane & 7) * 8, (short*)lA + chunk * 512);
            int brow = n0 + chunk * 8 + (lane >> 3);
            GLDS(Bt + (size_t)brow * K + k0 + (lane & 7) * 8, (short*)lB + chunk * 512);
        }
        __syncthreads();
        #pragma unroll
        for (int ks = 0; ks < 2; ks++) {
            s16x8 af[4], bfr[4];
            #pragma unroll
            for (int m = 0; m < 4; m++)
                af[m] = *(const s16x8*)&lA[(wr * 64 + m * 16 + l15) * 64 + ks * 32 + lg * 8];
            #pragma unroll
            for (int n = 0; n < 4; n++)
                bfr[n] = *(const s16x8*)&lB[(wc * 64 + n * 16 + l15) * 64 + ks * 32 + lg * 8];
            #pragma unroll
            for (int m = 0; m < 4; m++)
                #pragma unroll
                for (int n = 0; n < 4; n++)
                    acc[m][n] = MFMA16(af[m], bfr[n], acc[m][n]);
        }
        __syncthreads();
    }
    const int rbase = m0 + wr * 64, cbase = n0 + wc * 64;
    #pragma unroll
    for (int m = 0; m < 4; m++)
        #pragma unroll
        for (int n = 0; n < 4; n++) {
            int col = cbase + n * 16 + l15;
            int row0 = rbase + m * 16 + lg * 4;
            if (EPI == 0) {
                float* C = (float*)Cv;
                #pragma unroll
                for (int r = 0; r < 4; r++)
                    C[(size_t)(row0 + r) * N + col] = acc[m][n][r];
            } else {
                u16* C = (u16*)Cv;
                float bv = bias[col];
                #pragma unroll
                for (int r = 0; r < 4; r++)
                    C[(size_t)(row0 + r) * N + col] = bfbits(fmaxf(acc[m][n][r] + bv, 0.f));
            }
        }
}

// ---------------- GEMM 128x64 (for N=1024 shapes: more blocks, 2/CU) ----------------
__global__ __launch_bounds__(256) void gemm_bt64(const u16* __restrict__ A, const u16* __restrict__ Bt,
                                                 float* __restrict__ C, int M, int N, int K) {
    __shared__ __align__(16) short lA[128 * 64];
    __shared__ __align__(16) short lB[64 * 64];
    const int tid = threadIdx.x, lane = tid & 63, w = tid >> 6;
    const int l15 = lane & 15, lg = lane >> 4;
    const int m0 = blockIdx.y * 128, n0 = blockIdx.x * 64;
    f32x4 acc[2][4] = {};

    for (int k0 = 0; k0 < K; k0 += 64) {
        #pragma unroll
        for (int i = 0; i < 4; i++) {
            int chunk = w * 4 + i;
            int arow = m0 + chunk * 8 + (lane >> 3);
            GLDS(A + (size_t)arow * K + k0 + (lane & 7) * 8, (short*)lA + chunk * 512);
        }
        #pragma unroll
        for (int i = 0; i < 2; i++) {
            int chunk = w * 2 + i;
            int brow = n0 + chunk * 8 + (lane >> 3);
            GLDS(Bt + (size_t)brow * K + k0 + (lane & 7) * 8, (short*)lB + chunk * 512);
        }
        __syncthreads();
        #pragma unroll
        for (int ks = 0; ks < 2; ks++) {
            s16x8 af[2], bfr[4];
            #pragma unroll
            for (int m = 0; m < 2; m++)
                af[m] = *(const s16x8*)&lA[(w * 32 + m * 16 + l15) * 64 + ks * 32 + lg * 8];
            #pragma unroll
            for (int n = 0; n < 4; n++)
                bfr[n] = *(const s16x8*)&lB[(n * 16 + l15) * 64 + ks * 32 + lg * 8];
            #pragma unroll
            for (int m = 0; m < 2; m++)
                #pragma unroll
                for (int n = 0; n < 4; n++)
                    acc[m][n] = MFMA16(af[m], bfr[n], acc[m][n]);
        }
        __syncthreads();
    }
    #pragma unroll
    for (int m = 0; m < 2; m++)
        #pragma unroll
        for (int n = 0; n < 4; n++) {
            int col = n0 + n * 16 + l15;
            int row0 = m0 + w * 32 + m * 16 + lg * 4;
            #pragma unroll
            for (int r = 0; r < 4; r++)
                C[(size_t)(row0 + r) * N + col] = acc[m][n][r];
        }
}

// ---------------- QKV epilogue (strided QKV buffer): +bias, +rel -> two bf16 variants ----------------
__global__ void k_epi_qk2(const float* __restrict__ QKVf, int coff, const float* __restrict__ bias,
                          const float* __restrict__ rel, u16* __restrict__ Pa, u16* __restrict__ Pc, int n4) {
    int i = blockIdx.x * 256 + threadIdx.x;
    if (i >= n4) return;
    int f = i * 4;
    int row = f >> 10, col = f & 1023;
    float4 v = *(const float4*)(QKVf + (size_t)row * 3072 + coff + col);
    int d = f & 63;
    float4 b = *(const float4*)(bias + col);
    float4 r0 = *(const float4*)(rel + d);
    float4 r1 = *(const float4*)(rel + 64 + d);
    ushort4 oa, oc;
    oa.x = f2b(v.x + b.x + r0.x); oa.y = f2b(v.y + b.y + r0.y);
    oa.z = f2b(v.z + b.z + r0.z); oa.w = f2b(v.w + b.w + r0.w);
    oc.x = f2b(v.x + b.x + r1.x); oc.y = f2b(v.y + b.y + r1.y);
    oc.z = f2b(v.z + b.z + r1.z); oc.w = f2b(v.w + b.w + r1.w);
    ((ushort4*)Pa)[i] = oa;
    ((ushort4*)Pc)[i] = oc;
}

// ---------------- V transpose per group from strided QKV: -> Vt[g][d][l] bf16 ----------------
__global__ void k_vtrans2(const float* __restrict__ QKVf, const float* __restrict__ bv, u16* __restrict__ Vt) {
    __shared__ float t[64][65];
    const int g = blockIdx.y, lt = blockIdx.x;
    const int tx = threadIdx.x & 63, ty = threadIdx.x >> 6;  // 64 x 4
    const size_t gQ = (size_t)g * 65536;
    for (int i = 0; i < 64; i += 4) {
        int l = lt * 64 + ty + i;
        size_t f = gQ + (size_t)l * 64 + tx;  // flat index in [B*L, D] view
        t[ty + i][tx] = QKVf[(f >> 10) * 3072 + 2048 + (f & 1023)] + bv[f & 1023];
    }
    __syncthreads();
    for (int i = 0; i < 64; i += 4) {
        int d = ty + i;
        Vt[gQ + (size_t)d * 1024 + lt * 64 + tx] = f2b(t[tx][d]);
    }
}

// ---------------- fused dual-map attention ----------------
// grid (16 qtiles, 64 groups), 4 waves/block, wave w owns q rows qt*64+w*16 .. +15
__global__ __launch_bounds__(256) void k_attn(const u16* __restrict__ Qa, const u16* __restrict__ Qc,
                                              const u16* __restrict__ Ka, const u16* __restrict__ Kc,
                                              const u16* __restrict__ Vt,
                                              const float* __restrict__ adjm, const float* __restrict__ comm,
                                              u16* __restrict__ ctx) {
    const int g = blockIdx.y, qt = blockIdx.x;
    const int tid = threadIdx.x, lane = tid & 63, w = tid >> 6;
    const int l15 = lane & 15, lg = lane >> 4;
    __shared__ __align__(16) float lE[4][2][16][68];  // raw exp tiles, padded stride

    const int q0 = qt * 64 + w * 16;
    const size_t gQ = (size_t)g * 65536;
    const size_t mrow = (size_t)g * 1048576 + (size_t)(q0 + l15) * 1024;
    const float scale = 0.125f;

    s16x8 qa[2], qc[2];
    #pragma unroll
    for (int ks = 0; ks < 2; ks++) {
        size_t off = gQ + (size_t)(q0 + l15) * 64 + ks * 32 + lg * 8;
        qa[ks] = *(const s16x8*)(Qa + off);
        qc[ks] = *(const s16x8*)(Qc + off);
    }
    f32x4 ca[4] = {}, cc[4] = {};
    float la[4] = {0.f, 0.f, 0.f, 0.f}, lc[4] = {0.f, 0.f, 0.f, 0.f};

    #pragma unroll 1
    for (int kb = 0; kb < 1024; kb += 64) {
        // mask prefetch in PV A-fragment layout: row=q0+l15, cols kb+ks*32+lg*8..+7 (vectorized, early issue)
        float4 maf[2][2], mcf[2][2];
        #pragma unroll
        for (int ks = 0; ks < 2; ks++) {
            const float* pa_ = adjm + mrow + kb + ks * 32 + lg * 8;
            const float* pc_ = comm + mrow + kb + ks * 32 + lg * 8;
            maf[ks][0] = *(const float4*)pa_;
            maf[ks][1] = *(const float4*)(pa_ + 4);
            mcf[ks][0] = *(const float4*)pc_;
            mcf[ks][1] = *(const float4*)(pc_ + 4);
        }
        // QK^T for both maps
        f32x4 sa[4] = {}, sc[4] = {};
        #pragma unroll
        for (int ks = 0; ks < 2; ks++)
            #pragma unroll
            for (int n = 0; n < 4; n++) {
                size_t koff = gQ + (size_t)(kb + n * 16 + l15) * 64 + ks * 32 + lg * 8;
                s16x8 kfa = *(const s16x8*)(Ka + koff);
                s16x8 kfc = *(const s16x8*)(Kc + koff);
                sa[n] = MFMA16(qa[ks], kfa, sa[n]);
                sc[n] = MFMA16(qc[ks], kfc, sc[n]);
            }
        // exp (C-layout) -> LDS f32; per-lane partial row sums (reduction deferred past loop)
        #pragma unroll
        for (int n = 0; n < 4; n++)
            #pragma unroll
            for (int r = 0; r < 4; r++) {
                float ea = __expf(sa[n][r] * scale);
                float ec = __expf(sc[n][r] * scale);
                la[r] += ea;
                lc[r] += ec;
                lE[w][0][lg * 4 + r][n * 16 + l15] = ea;
                lE[w][1][lg * 4 + r][n * 16 + l15] = ec;
            }
        // PV: read exp in A-layout, multiply masks in-register, MFMA against V^T
        #pragma unroll
        for (int ks = 0; ks < 2; ks++) {
            const float* ea_p = &lE[w][0][l15][ks * 32 + lg * 8];
            const float* ec_p = &lE[w][1][l15][ks * 32 + lg * 8];
            float4 e0 = *(const float4*)ea_p, e1 = *(const float4*)(ea_p + 4);
            float4 f0 = *(const float4*)ec_p, f1 = *(const float4*)(ec_p + 4);
            union { s16x8 v; u16 u[8]; } pA, pC;
            pA.u[0] = bfbits(e0.x * maf[ks][0].x); pA.u[1] = bfbits(e0.y * maf[ks][0].y);
            pA.u[2] = bfbits(e0.z * maf[ks][0].z); pA.u[3] = bfbits(e0.w * maf[ks][0].w);
            pA.u[4] = bfbits(e1.x * maf[ks][1].x); pA.u[5] = bfbits(e1.y * maf[ks][1].y);
            pA.u[6] = bfbits(e1.z * maf[ks][1].z); pA.u[7] = bfbits(e1.w * maf[ks][1].w);
            pC.u[0] = bfbits(f0.x * mcf[ks][0].x); pC.u[1] = bfbits(f0.y * mcf[ks][0].y);
            pC.u[2] = bfbits(f0.z * mcf[ks][0].z); pC.u[3] = bfbits(f0.w * mcf[ks][0].w);
            pC.u[4] = bfbits(f1.x * mcf[ks][1].x); pC.u[5] = bfbits(f1.y * mcf[ks][1].y);
            pC.u[6] = bfbits(f1.z * mcf[ks][1].z); pC.u[7] = bfbits(f1.w * mcf[ks][1].w);
            #pragma unroll
            for (int d = 0; d < 4; d++) {
                s16x8 vf = *(const s16x8*)(Vt + gQ + (size_t)(d * 16 + l15) * 1024 + kb + ks * 32 + lg * 8);
                ca[d] = MFMA16(pA.v, vf, ca[d]);
                cc[d] = MFMA16(pC.v, vf, cc[d]);
            }
        }
    }
    // deferred softmax-denominator reduction over the 16-lane l15 group
    #pragma unroll
    for (int r = 0; r < 4; r++) {
        #pragma unroll
        for (int m = 8; m >= 1; m >>= 1) {
            la[r] += __shfl_xor(la[r], m);
            lc[r] += __shfl_xor(lc[r], m);
        }
    }
    #pragma unroll
    for (int r = 0; r < 4; r++) {
        float ila = 1.f / la[r], ilc = 1.f / lc[r];
        int row = q0 + lg * 4 + r;
        #pragma unroll
        for (int d = 0; d < 4; d++) {
            float v = ca[d][r] * ila + cc[d][r] * ilc;
            ctx[gQ + (size_t)row * 64 + d * 16 + l15] = f2b(v);
        }
    }
}

// ---------------- row LayerNorm: t = a[row]+bias+resid[row]; out = LN(t)*g+b (D=1024) ----------------
__global__ __launch_bounds__(256) void k_ln(const float* __restrict__ a, const float* __restrict__ bias,
                                            const float* __restrict__ resid, const float* __restrict__ gamma,
                                            const float* __restrict__ beta, float* __restrict__ out,
                                            u16* __restrict__ outb) {
    const int row = blockIdx.x, tid = threadIdx.x;
    const size_t base = (size_t)row * 1024 + tid * 4;
    float4 av = *(const float4*)(a + base);
    float4 rv = *(const float4*)(resid + base);
    float4 bv = *(const float4*)(bias + tid * 4);
    float t0 = av.x + rv.x + bv.x, t1 = av.y + rv.y + bv.y;
    float t2 = av.z + rv.z + bv.z, t3 = av.w + rv.w + bv.w;
    __shared__ float red[4];
    float s = t0 + t1 + t2 + t3;
    #pragma unroll
    for (int m = 32; m >= 1; m >>= 1) s += __shfl_xor(s, m);
    int w = tid >> 6;
    if ((tid & 63) == 0) red[w] = s;
    __syncthreads();
    float mean = (red[0] + red[1] + red[2] + red[3]) * (1.f / 1024.f);
    float d0 = t0 - mean, d1 = t1 - mean, d2 = t2 - mean, d3 = t3 - mean;
    float q = d0 * d0 + d1 * d1 + d2 * d2 + d3 * d3;
    __syncthreads();
    #pragma unroll
    for (int m = 32; m >= 1; m >>= 1) q += __shfl_xor(q, m);
    if ((tid & 63) == 0) red[w] = q;
    __syncthreads();
    float var = (red[0] + red[1] + red[2] + red[3]) * (1.f / 1024.f);
    float rs = rsqrtf(var + 1e-5f);
    float4 gv = *(const float4*)(gamma + tid * 4);
    float4 bev = *(const float4*)(beta + tid * 4);
    float o0 = d0 * rs * gv.x + bev.x, o1 = d1 * rs * gv.y + bev.y;
    float o2 = d2 * rs * gv.z + bev.z, o3 = d3 * rs * gv.w + bev.w;
    *(float4*)(out + base) = make_float4(o0, o1, o2, o3);
    if (outb) {
        ushort4 ob;
        ob.x = f2b(o0); ob.y = f2b(o1); ob.z = f2b(o2); ob.w = f2b(o3);
        *(ushort4*)(outb + base) = ob;
    }
}

extern "C" void kernel_launch(void* const* d_in, const int* in_sizes, int n_in,
                              void* d_out, int out_size, void* d_ws, size_t ws_size,
                              hipStream_t stream) {
    const float* x    = (const float*)d_in[0];
    const float* adjm = (const float*)d_in[1];
    const float* comm = (const float*)d_in[2];
    const float* rel  = (const float*)d_in[3];
    const float* Wq   = (const float*)d_in[4];
    const float* bq   = (const float*)d_in[5];
    const float* Wk   = (const float*)d_in[6];
    const float* bk   = (const float*)d_in[7];
    const float* Wv   = (const float*)d_in[8];
    const float* bv   = (const float*)d_in[9];
    const float* Wo   = (const float*)d_in[10];
    const float* bo   = (const float*)d_in[11];
    const float* g1   = (const float*)d_in[12];
    const float* be1  = (const float*)d_in[13];
    const float* W1   = (const float*)d_in[14];
    const float* b1   = (const float*)d_in[15];
    const float* W2   = (const float*)d_in[16];
    const float* b2   = (const float*)d_in[17];
    const float* g2   = (const float*)d_in[18];
    const float* be2  = (const float*)d_in[19];
    float* out = (float*)d_out;

    char* ws = (char*)d_ws;
    const size_t MB = 1048576;
    u16*   xb    = (u16*)(ws + 0 * MB);      // 8 MiB (dead after QKV gemm)
    u16*   Wqkvt = (u16*)(ws + 8 * MB);      // 6 MiB: Wqt[8,10) Wkt[10,12) Wvt[12,14)
    u16*   Wot   = (u16*)(ws + 14 * MB);     // 2 MiB
    u16*   W1t   = (u16*)(ws + 16 * MB);     // 8 MiB
    u16*   W2t   = (u16*)(ws + 24 * MB);     // 8 MiB (live through FFN2)
    float* QKVf  = (float*)(ws + 32 * MB);   // 48 MiB [32,80) (dead after epilogues)
    u16*   Qab   = (u16*)(ws + 80 * MB);     // 8 MiB each
    u16*   Qcb   = (u16*)(ws + 88 * MB);
    u16*   Kab   = (u16*)(ws + 96 * MB);
    u16*   Kcb   = (u16*)(ws + 104 * MB);
    u16*   Vtb   = (u16*)(ws + 112 * MB);
    u16*   ctx   = (u16*)(ws + 120 * MB);    // 8 MiB (dead after Wo gemm)
    float* ctxWo = (float*)(ws + 32 * MB);   // 16 MiB reuse QKVf
    float* out1  = (float*)(ws + 48 * MB);   // 16 MiB reuse (live to LN2)
    u16*   out1b = (u16*)(ws + 64 * MB);     // 8 MiB
    u16*   rb    = (u16*)(ws + 80 * MB);     // 32 MiB reuse attn bufs (FFN1 out, bf16)
    float* ff2   = (float*)(ws + 0 * MB);    // 16 MiB reuse xb+weights

    dim3 tb(32, 8);
    // 1. casts / weight prep
    k_f2b<<<4096, 256, 0, stream>>>(x, xb, 1048576);
    k_wtrans<<<dim3(32, 32), tb, 0, stream>>>(Wq, Wqkvt, 1024, 1024);
    k_wtrans<<<dim3(32, 32), tb, 0, stream>>>(Wk, Wqkvt + 1024 * 1024, 1024, 1024);
    k_wtrans<<<dim3(32, 32), tb, 0, stream>>>(Wv, Wqkvt + 2 * 1024 * 1024, 1024, 1024);
    k_wtrans<<<dim3(32, 32), tb, 0, stream>>>(Wo, Wot, 1024, 1024);
    k_wtrans<<<dim3(128, 32), tb, 0, stream>>>(W1, W1t, 1024, 4096);
    k_wtrans<<<dim3(32, 128), tb, 0, stream>>>(W2, W2t, 4096, 1024);
    // 2. fused QKV projection: [4096,1024] @ [3072,1024]^T -> [4096,3072]
    gemm_bt<0><<<dim3(24, 32), 256, 0, stream>>>(xb, Wqkvt, QKVf, 4096, 3072, 1024, nullptr);
    // 3. epilogues
    k_epi_qk2<<<4096, 256, 0, stream>>>(QKVf, 0, bq, rel, Qab, Qcb, 1048576);
    k_epi_qk2<<<4096, 256, 0, stream>>>(QKVf, 1024, bk, rel, Kab, Kcb, 1048576);
    k_vtrans2<<<dim3(16, 64), 256, 0, stream>>>(QKVf, bv, Vtb);
    // 4. dual-map attention
    k_attn<<<dim3(16, 64), 256, 0, stream>>>(Qab, Qcb, Kab, Kcb, Vtb, adjm, comm, ctx);
    // 5. output projection + LN1
    gemm_bt64<<<dim3(16, 32), 256, 0, stream>>>(ctx, Wot, ctxWo, 4096, 1024, 1024);
    k_ln<<<4096, 256, 0, stream>>>(ctxWo, bo, x, g1, be1, out1, out1b);
    // 6. FFN (FFN1 fuses bias+relu+bf16)
    gemm_bt<1><<<dim3(32, 32), 256, 0, stream>>>(out1b, W1t, rb, 4096, 4096, 1024, b1);
    gemm_bt64<<<dim3(16, 32), 256, 0, stream>>>(rb, W2t, ff2, 4096, 1024, 4096);
    // 7. LN2 -> final output
    k_ln<<<4096, 256, 0, stream>>>(ff2, b2, out1, g2, be2, out, nullptr);
}

// Round 3
// 657.741 us; speedup vs baseline: 1.0325x; 1.0325x over previous
//
#include <hip/hip_runtime.h>
#include <hip/hip_bf16.h>

typedef __attribute__((ext_vector_type(8))) short s16x8;
typedef __attribute__((ext_vector_type(4))) float f32x4;
typedef unsigned short u16;
typedef unsigned int u32;

__device__ __forceinline__ u16 f2b(float f) {
    u32 u = __float_as_uint(f);
    u32 r = (u + 0x7fffu + ((u >> 16) & 1u)) >> 16;  // RNE bf16
    return (u16)r;
}
__device__ __forceinline__ u16 bfbits(float f) {
    __hip_bfloat16 h = __float2bfloat16(f);
    return *reinterpret_cast<u16*>(&h);
}

#define MFMA16(a, b, c) __builtin_amdgcn_mfma_f32_16x16x32_bf16(a, b, c, 0, 0, 0)
#define GLDS(gp, lp)                                                              \
    __builtin_amdgcn_global_load_lds((const __attribute__((address_space(1))) void*)(gp), \
                                     (__attribute__((address_space(3))) void*)(lp), 16, 0, 0)

// ---------------- elementwise: f32 -> bf16 ----------------
__global__ void k_f2b(const float* __restrict__ in, u16* __restrict__ out, int n4) {
    int i = blockIdx.x * 256 + threadIdx.x;
    if (i >= n4) return;
    float4 v = ((const float4*)in)[i];
    ushort4 o;
    o.x = f2b(v.x); o.y = f2b(v.y); o.z = f2b(v.z); o.w = f2b(v.w);
    ((ushort4*)out)[i] = o;
}

// ---------------- weight transpose+convert: W[K,N] f32 -> Wt[N,K] bf16 ----------------
__global__ void k_wtrans(const float* __restrict__ W, u16* __restrict__ Wt, int K, int N) {
    __shared__ float t[32][33];
    int bx = blockIdx.x * 32, by = blockIdx.y * 32;
    int tx = threadIdx.x, ty = threadIdx.y;
    for (int i = 0; i < 32; i += 8)
        t[ty + i][tx] = W[(size_t)(by + ty + i) * N + bx + tx];
    __syncthreads();
    for (int i = 0; i < 32; i += 8)
        Wt[(size_t)(bx + ty + i) * K + by + tx] = f2b(t[tx][ty + i]);
}

// ---------------- GEMM 128x128: C = A @ Bt^T.  EPI 0: f32 store. EPI 1: bf16(relu(acc+bias)) ----------------
template <int EPI>
__global__ __launch_bounds__(256) void gemm_bt(const u16* __restrict__ A, const u16* __restrict__ Bt,
                                               void* __restrict__ Cv, int M, int N, int K,
                                               const float* __restrict__ bias) {
    __shared__ __align__(16) short lA[128 * 64];
    __shared__ __align__(16) short lB[128 * 64];
    const int tid = threadIdx.x, lane = tid & 63, w = tid >> 6;
    const int l15 = lane & 15, lg = lane >> 4;
    const int bm = blockIdx.y, bn = blockIdx.x;
    const int wr = w >> 1, wc = w & 1;
    const int m0 = bm * 128, n0 = bn * 128;
    f32x4 acc[4][4] = {};

    for (int k0 = 0; k0 < K; k0 += 64) {
        #pragma unroll
        for (int i = 0; i < 4; i++) {
            int chunk = w * 4 + i;
            int arow = m0 + chunk * 8 + (lane >> 3);
            GLDS(A + (size_t)arow * K + k0 + (lane & 7) * 8, (short*)lA + chunk * 512);
            int brow = n0 + chunk * 8 + (lane >> 3);
            GLDS(Bt + (size_t)brow * K + k0 + (lane & 7) * 8, (short*)lB + chunk * 512);
        }
        __syncthreads();
        #pragma unroll
        for (int ks = 0; ks < 2; ks++) {
            s16x8 af[4], bfr[4];
            #pragma unroll
            for (int m = 0; m < 4; m++)
                af[m] = *(const s16x8*)&lA[(wr * 64 + m * 16 + l15) * 64 + ks * 32 + lg * 8];
            #pragma unroll
            for (int n = 0; n < 4; n++)
                bfr[n] = *(const s16x8*)&lB[(wc * 64 + n * 16 + l15) * 64 + ks * 32 + lg * 8];
            #pragma unroll
            for (int m = 0; m < 4; m++)
                #pragma unroll
                for (int n = 0; n < 4; n++)
                    acc[m][n] = MFMA16(af[m], bfr[n], acc[m][n]);
        }
        __syncthreads();
    }
    const int rbase = m0 + wr * 64, cbase = n0 + wc * 64;
    #pragma unroll
    for (int m = 0; m < 4; m++)
        #pragma unroll
        for (int n = 0; n < 4; n++) {
            int col = cbase + n * 16 + l15;
            int row0 = rbase + m * 16 + lg * 4;
            if (EPI == 0) {
                float* C = (float*)Cv;
                #pragma unroll
                for (int r = 0; r < 4; r++)
                    C[(size_t)(row0 + r) * N + col] = acc[m][n][r];
            } else {
                u16* C = (u16*)Cv;
                float bv = bias[col];
                #pragma unroll
                for (int r = 0; r < 4; r++)
                    C[(size_t)(row0 + r) * N + col] = bfbits(fmaxf(acc[m][n][r] + bv, 0.f));
            }
        }
}

// ---------------- GEMM 128x64 (for N=1024 shapes: more blocks, 2/CU) ----------------
__global__ __launch_bounds__(256) void gemm_bt64(const u16* __restrict__ A, const u16* __restrict__ Bt,
                                                 float* __restrict__ C, int M, int N, int K) {
    __shared__ __align__(16) short lA[128 * 64];
    __shared__ __align__(16) short lB[64 * 64];
    const int tid = threadIdx.x, lane = tid & 63, w = tid >> 6;
    const int l15 = lane & 15, lg = lane >> 4;
    const int m0 = blockIdx.y * 128, n0 = blockIdx.x * 64;
    f32x4 acc[2][4] = {};

    for (int k0 = 0; k0 < K; k0 += 64) {
        #pragma unroll
        for (int i = 0; i < 4; i++) {
            int chunk = w * 4 + i;
            int arow = m0 + chunk * 8 + (lane >> 3);
            GLDS(A + (size_t)arow * K + k0 + (lane & 7) * 8, (short*)lA + chunk * 512);
        }
        #pragma unroll
        for (int i = 0; i < 2; i++) {
            int chunk = w * 2 + i;
            int brow = n0 + chunk * 8 + (lane >> 3);
            GLDS(Bt + (size_t)brow * K + k0 + (lane & 7) * 8, (short*)lB + chunk * 512);
        }
        __syncthreads();
        #pragma unroll
        for (int ks = 0; ks < 2; ks++) {
            s16x8 af[2], bfr[4];
            #pragma unroll
            for (int m = 0; m < 2; m++)
                af[m] = *(const s16x8*)&lA[(w * 32 + m * 16 + l15) * 64 + ks * 32 + lg * 8];
            #pragma unroll
            for (int n = 0; n < 4; n++)
                bfr[n] = *(const s16x8*)&lB[(n * 16 + l15) * 64 + ks * 32 + lg * 8];
            #pragma unroll
            for (int m = 0; m < 2; m++)
                #pragma unroll
                for (int n = 0; n < 4; n++)
                    acc[m][n] = MFMA16(af[m], bfr[n], acc[m][n]);
        }
        __syncthreads();
    }
    #pragma unroll
    for (int m = 0; m < 2; m++)
        #pragma unroll
        for (int n = 0; n < 4; n++) {
            int col = n0 + n * 16 + l15;
            int row0 = m0 + w * 32 + m * 16 + lg * 4;
            #pragma unroll
            for (int r = 0; r < 4; r++)
                C[(size_t)(row0 + r) * N + col] = acc[m][n][r];
        }
}

// ---------------- QKV epilogue (strided QKV buffer): +bias, +rel -> two bf16 variants ----------------
__global__ void k_epi_qk2(const float* __restrict__ QKVf, int coff, const float* __restrict__ bias,
                          const float* __restrict__ rel, u16* __restrict__ Pa, u16* __restrict__ Pc, int n4) {
    int i = blockIdx.x * 256 + threadIdx.x;
    if (i >= n4) return;
    int f = i * 4;
    int row = f >> 10, col = f & 1023;
    float4 v = *(const float4*)(QKVf + (size_t)row * 3072 + coff + col);
    int d = f & 63;
    float4 b = *(const float4*)(bias + col);
    float4 r0 = *(const float4*)(rel + d);
    float4 r1 = *(const float4*)(rel + 64 + d);
    ushort4 oa, oc;
    oa.x = f2b(v.x + b.x + r0.x); oa.y = f2b(v.y + b.y + r0.y);
    oa.z = f2b(v.z + b.z + r0.z); oa.w = f2b(v.w + b.w + r0.w);
    oc.x = f2b(v.x + b.x + r1.x); oc.y = f2b(v.y + b.y + r1.y);
    oc.z = f2b(v.z + b.z + r1.z); oc.w = f2b(v.w + b.w + r1.w);
    ((ushort4*)Pa)[i] = oa;
    ((ushort4*)Pc)[i] = oc;
}

// ---------------- V transpose per group from strided QKV: -> Vt[g][d][l] bf16 ----------------
__global__ void k_vtrans2(const float* __restrict__ QKVf, const float* __restrict__ bv, u16* __restrict__ Vt) {
    __shared__ float t[64][65];
    const int g = blockIdx.y, lt = blockIdx.x;
    const int tx = threadIdx.x & 63, ty = threadIdx.x >> 6;  // 64 x 4
    const size_t gQ = (size_t)g * 65536;
    for (int i = 0; i < 64; i += 4) {
        int l = lt * 64 + ty + i;
        size_t f = gQ + (size_t)l * 64 + tx;  // flat index in [B*L, D] view
        t[ty + i][tx] = QKVf[(f >> 10) * 3072 + 2048 + (f & 1023)] + bv[f & 1023];
    }
    __syncthreads();
    for (int i = 0; i < 64; i += 4) {
        int d = ty + i;
        Vt[gQ + (size_t)d * 1024 + lt * 64 + tx] = f2b(t[tx][d]);
    }
}

// ---------------- single-map attention, map split across gridDim.z ----------------
// grid (16 qtiles, 64 groups, 2 maps), 4 waves/block, wave w owns q rows qt*64+w*16..+15.
// Writes per-map ctx/denom (f32); k_comb sums the two maps.
__global__ __launch_bounds__(256) void k_attn1(const u16* __restrict__ Qa, const u16* __restrict__ Qc,
                                               const u16* __restrict__ Ka, const u16* __restrict__ Kc,
                                               const u16* __restrict__ Vt,
                                               const float* __restrict__ adjm, const float* __restrict__ comm,
                                               float* __restrict__ ctxA, float* __restrict__ ctxC) {
    const int g = blockIdx.y, qt = blockIdx.x, s = blockIdx.z;
    const u16* __restrict__ Q = s ? Qc : Qa;
    const u16* __restrict__ K = s ? Kc : Ka;
    const float* __restrict__ mask = s ? comm : adjm;
    float* __restrict__ ctxp = s ? ctxC : ctxA;

    const int tid = threadIdx.x, lane = tid & 63, w = tid >> 6;
    const int l15 = lane & 15, lg = lane >> 4;
    __shared__ __align__(16) float lE[4][16][68];  // per-wave exp tile, padded stride

    const int q0 = qt * 64 + w * 16;
    const size_t gQ = (size_t)g * 65536;
    const float* __restrict__ mrow = mask + (size_t)g * 1048576 + (size_t)(q0 + l15) * 1024;
    const float scale = 0.125f;

    s16x8 qf[2];
    #pragma unroll
    for (int ks = 0; ks < 2; ks++)
        qf[ks] = *(const s16x8*)(Q + gQ + (size_t)(q0 + l15) * 64 + ks * 32 + lg * 8);

    f32x4 ca[4] = {};
    float la[4] = {0.f, 0.f, 0.f, 0.f};

    // prefetch masks for kb=0 (PV A-frag layout: row q0+l15, cols kb+ks*32+lg*8..+7)
    float4 mc[2][2], mn[2][2];
    #pragma unroll
    for (int ks = 0; ks < 2; ks++) {
        const float* p = mrow + ks * 32 + lg * 8;
        mc[ks][0] = *(const float4*)p;
        mc[ks][1] = *(const float4*)(p + 4);
    }

    #pragma unroll 2
    for (int kb = 0; kb < 1024; kb += 64) {
        // issue NEXT iteration's mask loads (loop-carried prefetch, ~1 iter of latency slack)
        const int kbn = (kb + 64) & 1023;
        #pragma unroll
        for (int ks = 0; ks < 2; ks++) {
            const float* p = mrow + kbn + ks * 32 + lg * 8;
            mn[ks][0] = *(const float4*)p;
            mn[ks][1] = *(const float4*)(p + 4);
        }
        // QK^T
        f32x4 sa[4] = {};
        #pragma unroll
        for (int ks = 0; ks < 2; ks++)
            #pragma unroll
            for (int n = 0; n < 4; n++) {
                s16x8 kf = *(const s16x8*)(K + gQ + (size_t)(kb + n * 16 + l15) * 64 + ks * 32 + lg * 8);
                sa[n] = MFMA16(qf[ks], kf, sa[n]);
            }
        // exp (C-layout) -> LDS; per-lane partial row sums
        #pragma unroll
        for (int n = 0; n < 4; n++)
            #pragma unroll
            for (int r = 0; r < 4; r++) {
                float e = __expf(sa[n][r] * scale);
                la[r] += e;
                lE[w][lg * 4 + r][n * 16 + l15] = e;
            }
        // PV: read exp in A-layout, multiply prefetched masks in-register, MFMA vs V^T
        #pragma unroll
        for (int ks = 0; ks < 2; ks++) {
            const float* ep = &lE[w][l15][ks * 32 + lg * 8];
            float4 e0 = *(const float4*)ep, e1 = *(const float4*)(ep + 4);
            union { s16x8 v; u16 u[8]; } pf;
            pf.u[0] = bfbits(e0.x * mc[ks][0].x); pf.u[1] = bfbits(e0.y * mc[ks][0].y);
            pf.u[2] = bfbits(e0.z * mc[ks][0].z); pf.u[3] = bfbits(e0.w * mc[ks][0].w);
            pf.u[4] = bfbits(e1.x * mc[ks][1].x); pf.u[5] = bfbits(e1.y * mc[ks][1].y);
            pf.u[6] = bfbits(e1.z * mc[ks][1].z); pf.u[7] = bfbits(e1.w * mc[ks][1].w);
            #pragma unroll
            for (int d = 0; d < 4; d++) {
                s16x8 vf = *(const s16x8*)(Vt + gQ + (size_t)(d * 16 + l15) * 1024 + kb + ks * 32 + lg * 8);
                ca[d] = MFMA16(pf.v, vf, ca[d]);
            }
        }
        // rotate prefetched masks
        #pragma unroll
        for (int ks = 0; ks < 2; ks++) {
            mc[ks][0] = mn[ks][0];
            mc[ks][1] = mn[ks][1];
        }
    }
    // deferred denominator reduction over the 16-lane l15 group
    #pragma unroll
    for (int r = 0; r < 4; r++)
        #pragma unroll
        for (int m = 8; m >= 1; m >>= 1)
            la[r] += __shfl_xor(la[r], m);
    #pragma unroll
    for (int r = 0; r < 4; r++) {
        float il = 1.f / la[r];
        int row = q0 + lg * 4 + r;
        #pragma unroll
        for (int d = 0; d < 4; d++)
            ctxp[gQ + (size_t)row * 64 + d * 16 + l15] = ca[d][r] * il;
    }
}

// ---------------- combine the two maps' normalized partial contexts -> bf16 ----------------
__global__ void k_comb(const float* __restrict__ A, const float* __restrict__ C,
                       u16* __restrict__ out, int n4) {
    int i = blockIdx.x * 256 + threadIdx.x;
    if (i >= n4) return;
    float4 a = ((const float4*)A)[i];
    float4 c = ((const float4*)C)[i];
    ushort4 o;
    o.x = f2b(a.x + c.x); o.y = f2b(a.y + c.y);
    o.z = f2b(a.z + c.z); o.w = f2b(a.w + c.w);
    ((ushort4*)out)[i] = o;
}

// ---------------- row LayerNorm: t = a[row]+bias+resid[row]; out = LN(t)*g+b (D=1024) ----------------
__global__ __launch_bounds__(256) void k_ln(const float* __restrict__ a, const float* __restrict__ bias,
                                            const float* __restrict__ resid, const float* __restrict__ gamma,
                                            const float* __restrict__ beta, float* __restrict__ out,
                                            u16* __restrict__ outb) {
    const int row = blockIdx.x, tid = threadIdx.x;
    const size_t base = (size_t)row * 1024 + tid * 4;
    float4 av = *(const float4*)(a + base);
    float4 rv = *(const float4*)(resid + base);
    float4 bv = *(const float4*)(bias + tid * 4);
    float t0 = av.x + rv.x + bv.x, t1 = av.y + rv.y + bv.y;
    float t2 = av.z + rv.z + bv.z, t3 = av.w + rv.w + bv.w;
    __shared__ float red[4];
    float s = t0 + t1 + t2 + t3;
    #pragma unroll
    for (int m = 32; m >= 1; m >>= 1) s += __shfl_xor(s, m);
    int w = tid >> 6;
    if ((tid & 63) == 0) red[w] = s;
    __syncthreads();
    float mean = (red[0] + red[1] + red[2] + red[3]) * (1.f / 1024.f);
    float d0 = t0 - mean, d1 = t1 - mean, d2 = t2 - mean, d3 = t3 - mean;
    float q = d0 * d0 + d1 * d1 + d2 * d2 + d3 * d3;
    __syncthreads();
    #pragma unroll
    for (int m = 32; m >= 1; m >>= 1) q += __shfl_xor(q, m);
    if ((tid & 63) == 0) red[w] = q;
    __syncthreads();
    float var = (red[0] + red[1] + red[2] + red[3]) * (1.f / 1024.f);
    float rs = rsqrtf(var + 1e-5f);
    float4 gv = *(const float4*)(gamma + tid * 4);
    float4 bev = *(const float4*)(beta + tid * 4);
    float o0 = d0 * rs * gv.x + bev.x, o1 = d1 * rs * gv.y + bev.y;
    float o2 = d2 * rs * gv.z + bev.z, o3 = d3 * rs * gv.w + bev.w;
    *(float4*)(out + base) = make_float4(o0, o1, o2, o3);
    if (outb) {
        ushort4 ob;
        ob.x = f2b(o0); ob.y = f2b(o1); ob.z = f2b(o2); ob.w = f2b(o3);
        *(ushort4*)(outb + base) = ob;
    }
}

extern "C" void kernel_launch(void* const* d_in, const int* in_sizes, int n_in,
                              void* d_out, int out_size, void* d_ws, size_t ws_size,
                              hipStream_t stream) {
    const float* x    = (const float*)d_in[0];
    const float* adjm = (const float*)d_in[1];
    const float* comm = (const float*)d_in[2];
    const float* rel  = (const float*)d_in[3];
    const float* Wq   = (const float*)d_in[4];
    const float* bq   = (const float*)d_in[5];
    const float* Wk   = (const float*)d_in[6];
    const float* bk   = (const float*)d_in[7];
    const float* Wv   = (const float*)d_in[8];
    const float* bv   = (const float*)d_in[9];
    const float* Wo   = (const float*)d_in[10];
    const float* bo   = (const float*)d_in[11];
    const float* g1   = (const float*)d_in[12];
    const float* be1  = (const float*)d_in[13];
    const float* W1   = (const float*)d_in[14];
    const float* b1   = (const float*)d_in[15];
    const float* W2   = (const float*)d_in[16];
    const float* b2   = (const float*)d_in[17];
    const float* g2   = (const float*)d_in[18];
    const float* be2  = (const float*)d_in[19];
    float* out = (float*)d_out;

    char* ws = (char*)d_ws;
    const size_t MB = 1048576;
    u16*   xb    = (u16*)(ws + 0 * MB);      // 8 MiB (dead after QKV gemm)
    u16*   Wqkvt = (u16*)(ws + 8 * MB);      // 6 MiB
    u16*   Wot   = (u16*)(ws + 14 * MB);     // 2 MiB
    u16*   W1t   = (u16*)(ws + 16 * MB);     // 8 MiB
    u16*   W2t   = (u16*)(ws + 24 * MB);     // 8 MiB
    float* QKVf  = (float*)(ws + 32 * MB);   // 48 MiB [32,80)
    u16*   Qab   = (u16*)(ws + 80 * MB);     // 8 MiB each [80,120)
    u16*   Qcb   = (u16*)(ws + 88 * MB);
    u16*   Kab   = (u16*)(ws + 96 * MB);
    u16*   Kcb   = (u16*)(ws + 104 * MB);
    u16*   Vtb   = (u16*)(ws + 112 * MB);
    float* ctxA  = (float*)(ws + 120 * MB);  // 16 MiB
    float* ctxC  = (float*)(ws + 136 * MB);  // 16 MiB
    u16*   ctx   = (u16*)(ws + 152 * MB);    // 8 MiB
    float* ctxWo = (float*)(ws + 32 * MB);   // reuse QKVf
    float* out1  = (float*)(ws + 48 * MB);   // live to LN2
    u16*   out1b = (u16*)(ws + 64 * MB);
    u16*   rb    = (u16*)(ws + 80 * MB);     // 32 MiB reuse attn inputs (dead)
    float* ff2   = (float*)(ws + 0 * MB);    // 16 MiB reuse

    dim3 tb(32, 8);
    // 1. casts / weight prep
    k_f2b<<<4096, 256, 0, stream>>>(x, xb, 1048576);
    k_wtrans<<<dim3(32, 32), tb, 0, stream>>>(Wq, Wqkvt, 1024, 1024);
    k_wtrans<<<dim3(32, 32), tb, 0, stream>>>(Wk, Wqkvt + 1024 * 1024, 1024, 1024);
    k_wtrans<<<dim3(32, 32), tb, 0, stream>>>(Wv, Wqkvt + 2 * 1024 * 1024, 1024, 1024);
    k_wtrans<<<dim3(32, 32), tb, 0, stream>>>(Wo, Wot, 1024, 1024);
    k_wtrans<<<dim3(128, 32), tb, 0, stream>>>(W1, W1t, 1024, 4096);
    k_wtrans<<<dim3(32, 128), tb, 0, stream>>>(W2, W2t, 4096, 1024);
    // 2. fused QKV projection
    gemm_bt<0><<<dim3(24, 32), 256, 0, stream>>>(xb, Wqkvt, QKVf, 4096, 3072, 1024, nullptr);
    // 3. epilogues
    k_epi_qk2<<<4096, 256, 0, stream>>>(QKVf, 0, bq, rel, Qab, Qcb, 1048576);
    k_epi_qk2<<<4096, 256, 0, stream>>>(QKVf, 1024, bk, rel, Kab, Kcb, 1048576);
    k_vtrans2<<<dim3(16, 64), 256, 0, stream>>>(QKVf, bv, Vtb);
    // 4. dual-map attention: map-split blocks + combine
    k_attn1<<<dim3(16, 64, 2), 256, 0, stream>>>(Qab, Qcb, Kab, Kcb, Vtb, adjm, comm, ctxA, ctxC);
    k_comb<<<4096, 256, 0, stream>>>(ctxA, ctxC, ctx, 1048576);
    // 5. output projection + LN1
    gemm_bt64<<<dim3(16, 32), 256, 0, stream>>>(ctx, Wot, ctxWo, 4096, 1024, 1024);
    k_ln<<<4096, 256, 0, stream>>>(ctxWo, bo, x, g1, be1, out1, out1b);
    // 6. FFN
    gemm_bt<1><<<dim3(32, 32), 256, 0, stream>>>(out1b, W1t, rb, 4096, 4096, 1024, b1);
    gemm_bt64<<<dim3(16, 32), 256, 0, stream>>>(rb, W2t, ff2, 4096, 1024, 4096);
    // 7. LN2 -> final output
    k_ln<<<4096, 256, 0, stream>>>(ff2, b2, out1, g2, be2, out, nullptr);
}